// Round 1
// baseline (28.945 us; speedup 1.0000x reference)
//
#include <hip/hip_runtime.h>

// YOLOLayer: B=16, NA=3, NC=80, G=64, stride=8
// in : x[B][NA*85][64][64] f32
// out: boxes[B][NA*4096][4] ++ conf[B][NA*4096] ++ cls[B][NA*4096][80]  (flat f32)

#define NB 16
#define NA 3
#define NC 80
#define GG 4096   // 64*64
#define CH 85     // 5 + NC

__device__ __forceinline__ float sigmoidf(float v) {
    return 1.0f / (1.0f + __expf(-v));
}

__global__ __launch_bounds__(256) void yolo_kernel(const float* __restrict__ x,
                                                   float* __restrict__ out) {
    constexpr int S = 64;                 // spatial positions per block
    __shared__ float lds[CH][S + 1];      // +1 pad: conflict-free transposed reads

    const int tilesPer = GG / S;          // 64
    int blk  = blockIdx.x;
    int tile = blk % tilesPer;
    int ba   = blk / tilesPer;            // b*NA + a
    int a    = ba % NA;
    int s0   = tile * S;

    // ---- stage input tile: 85 channels x 64 positions, coalesced ----
    const float* __restrict__ xin = x + (size_t)ba * CH * GG + s0;
    for (int i = threadIdx.x; i < CH * S; i += 256) {
        int ch = i >> 6;                  // S == 64
        int p  = i & 63;
        lds[ch][p] = xin[(size_t)ch * GG + p];
    }
    __syncthreads();

    // anchors scaled by g (=64) and STRIDE (=8); *8 is exact scaling so
    // this matches the reference's (exp(w)*aw*64)*8 order bit-for-bit.
    const float anchor_w[NA] = {0.1f * 64 * 8, 0.3f * 64 * 8, 0.6f * 64 * 8};
    const float anchor_h[NA] = {0.13f * 64 * 8, 0.35f * 64 * 8, 0.55f * 64 * 8};

    const int loc = ba * GG + s0;         // flat (b,a,spatial) base
    float* __restrict__ boxes = out;                                  // [..][4]
    float* __restrict__ conf  = out + (size_t)NB * NA * GG * 4;       // 786432
    float* __restrict__ cls   = out + (size_t)NB * NA * GG * 5;       // 983040

    // ---- boxes + conf: one thread per position (first wave) ----
    if (threadIdx.x < S) {
        int p  = threadIdx.x;
        int sp = s0 + p;
        float gx = (float)(sp & 63);      // grid_x along last dim
        float gy = (float)(sp >> 6);      // grid_y along dim -2
        float4 bx;
        bx.x = (sigmoidf(lds[0][p]) + gx) * 8.0f;
        bx.y = (sigmoidf(lds[1][p]) + gy) * 8.0f;
        bx.z = __expf(lds[2][p]) * anchor_w[a];
        bx.w = __expf(lds[3][p]) * anchor_h[a];
        reinterpret_cast<float4*>(boxes)[loc + p] = bx;               // 16B store
        conf[loc + p] = sigmoidf(lds[4][p]);
    }

    // ---- cls: 80*64 contiguous outputs; consecutive threads -> contiguous ----
    float* __restrict__ clsBase = cls + (size_t)loc * NC;
    for (int i = threadIdx.x; i < NC * S; i += 256) {
        int p = i / NC;
        int c = i - p * NC;
        clsBase[i] = sigmoidf(lds[5 + c][p]);   // lds stride 65 -> bank-conflict-free
    }
}

extern "C" void kernel_launch(void* const* d_in, const int* in_sizes, int n_in,
                              void* d_out, int out_size, void* d_ws, size_t ws_size,
                              hipStream_t stream) {
    const float* x = (const float*)d_in[0];
    float* out = (float*)d_out;
    dim3 grid(NB * NA * (GG / 64));       // 3072 blocks
    yolo_kernel<<<grid, 256, 0, stream>>>(x, out);
}

// Round 2
// 27.442 us; speedup vs baseline: 1.0548x; 1.0548x over previous
//
#include <hip/hip_runtime.h>

// YOLOLayer: B=16, NA=3, NC=80, G=64, stride=8
// in : x[B][NA*85][64][64] f32
// out: boxes[B*NA*4096][4] ++ conf[B*NA*4096] ++ cls[B*NA*4096][80]  (flat f32)

#define NB 16
#define NA 3
#define NC 80
#define GG 4096   // 64*64
#define CH 85     // 5 + NC
#define S  128    // spatial positions per block

__device__ __forceinline__ float sigmoidf(float v) {
    return 1.0f / (1.0f + __expf(-v));
}

// Swizzled LDS float-index for (channel, position). Row stride = S floats
// (no pad, keeps 16B alignment). Granule-level XOR with (ch>>2)&7 mixes the
// "rows 4 apart" cls read pattern across all 8 bank-groups.
__device__ __forceinline__ int lidx(int ch, int p) {
    int g = (p >> 2) ^ ((ch >> 2) & 7);
    return ch * S + (g << 2) + (p & 3);
}

__global__ __launch_bounds__(512) void yolo_kernel(const float* __restrict__ x,
                                                   float* __restrict__ out) {
    __shared__ float lds[CH * S];         // 42.5 KB -> 3 blocks/CU, 24 waves

    const int tilesPer = GG / S;          // 32
    int blk  = blockIdx.x;
    int tile = blk & (tilesPer - 1);
    int ba   = blk / tilesPer;            // b*NA + a
    int a    = ba % NA;
    int s0   = tile * S;

    // ---- stage: 85 channels x 128 positions, float4 loads (512B/row chunk) ----
    const float4* __restrict__ xin4 =
        reinterpret_cast<const float4*>(x + (size_t)ba * CH * GG + s0);
    for (int i = threadIdx.x; i < CH * (S / 4); i += 512) {   // 2720 granules
        int ch = i >> 5;                  // S/4 == 32 granules per row
        int p4 = i & 31;
        int g  = p4 ^ ((ch >> 2) & 7);    // swizzled write, conflict-free
        float4 v = xin4[ch * (GG / 4) + p4];
        *reinterpret_cast<float4*>(&lds[ch * S + (g << 2)]) = v;
    }
    __syncthreads();

    // anchors scaled by g(=64) and STRIDE(=8): exact *8 scaling matches ref.
    const float anchor_w[NA] = {0.1f * 64 * 8, 0.3f * 64 * 8, 0.6f * 64 * 8};
    const float anchor_h[NA] = {0.13f * 64 * 8, 0.35f * 64 * 8, 0.55f * 64 * 8};

    const int loc = ba * GG + s0;
    float* __restrict__ boxes = out;                              // [..][4]
    float* __restrict__ conf  = out + (size_t)NB * NA * GG * 4;   // 786432
    float* __restrict__ cls   = out + (size_t)NB * NA * GG * 5;   // 983040

    // ---- boxes + conf: one thread per position ----
    if (threadIdx.x < S) {
        int p  = threadIdx.x;
        int sp = s0 + p;
        float gx = (float)(sp & 63);      // grid_x along last dim
        float gy = (float)(sp >> 6);      // grid_y along dim -2
        float4 bx;
        bx.x = (sigmoidf(lds[lidx(0, p)]) + gx) * 8.0f;
        bx.y = (sigmoidf(lds[lidx(1, p)]) + gy) * 8.0f;
        bx.z = __expf(lds[lidx(2, p)]) * anchor_w[a];
        bx.w = __expf(lds[lidx(3, p)]) * anchor_h[a];
        reinterpret_cast<float4*>(boxes)[loc + p] = bx;           // 16B store
        conf[loc + p] = sigmoidf(lds[lidx(4, p)]);
    }

    // ---- cls: 80x128 outputs, float4 stores (contiguous across lanes) ----
    float4* __restrict__ cls4 =
        reinterpret_cast<float4*>(cls + (size_t)loc * NC);
    for (int i = threadIdx.x; i < NC * (S / 4); i += 512) {       // 2560
        int p  = i / 20;                  // position
        int c4 = i % 20;                  // class-quad
        int r  = 5 + (c4 << 2);
        float4 v;
        v.x = sigmoidf(lds[lidx(r + 0, p)]);
        v.y = sigmoidf(lds[lidx(r + 1, p)]);
        v.z = sigmoidf(lds[lidx(r + 2, p)]);
        v.w = sigmoidf(lds[lidx(r + 3, p)]);
        cls4[i] = v;
    }
}

extern "C" void kernel_launch(void* const* d_in, const int* in_sizes, int n_in,
                              void* d_out, int out_size, void* d_ws, size_t ws_size,
                              hipStream_t stream) {
    const float* x = (const float*)d_in[0];
    float* out = (float*)d_out;
    dim3 grid(NB * NA * (GG / S));        // 1536 blocks
    yolo_kernel<<<grid, 512, 0, stream>>>(x, out);
}